// Round 6
// baseline (321.634 us; speedup 1.0000x reference)
//
#include <hip/hip_runtime.h>
#include <stdint.h>

// CrossAttentionHead: B=8, C=768, S=T=2304, D=512.
// transpose/cvt -> fused QKV GEMM (BK=64) -> scores128 (BK=64, exp epilogue +
// atomic row denom) -> PV GEMM split-K=2 (BK=64, raw fp32 partials) ->
// combine (out = (p0+p1)/denom).
//
// Round-6: BK=64 halves vmcnt-drain+barrier count per K (the 2ph critical
// path, m233); PV split-K=2 doubles PV TLP (2.25 -> 4.5 blocks/CU).
//
// Workspace (ushort elems):
//   Q[0,..) K[9437184,..) Vt[18874368,..)  (each 9,437,184)
//   PV partial (fp32, 9437184) aliases Q+K region (dead during PV).
//   P@28311552 (42,467,328 elems, 85MB); aliased inside P (dead before P):
//   xs@28311552, xts@42467328, wcat@56623104 (wq|wk|wv, 1536x768),
//   bcat(f32)@ushort 57802752; denom(f32,18432)@ushort 70778880.

typedef __bf16 bf16x8 __attribute__((ext_vector_type(8)));
typedef float f32x4 __attribute__((ext_vector_type(4)));

__device__ __forceinline__ unsigned short f2bf(float f) {
  union { float f; unsigned int u; } c; c.f = f;
  return (unsigned short)((c.u + 0x7fffu + ((c.u >> 16) & 1u)) >> 16); // RNE
}

// ---- all three weights fp32 -> bf16 into contiguous wcat ----
__global__ __launch_bounds__(256) void convw3_kernel(const float* __restrict__ wq,
                                                     const float* __restrict__ wk,
                                                     const float* __restrict__ wv,
                                                     unsigned short* __restrict__ wcat) {
  int i = (blockIdx.x * 256 + threadIdx.x) * 4;  // 0 .. 1179644
  const float* src = (i < 393216) ? wq : (i < 786432) ? wk : wv;
  const int off = (i < 393216) ? 0 : (i < 786432) ? 393216 : 786432;
  const float4 v = *reinterpret_cast<const float4*>(src + (i - off));
  wcat[i + 0] = f2bf(v.x); wcat[i + 1] = f2bf(v.y);
  wcat[i + 2] = f2bf(v.z); wcat[i + 3] = f2bf(v.w);
}

// ---- zero denom + concat bias ----
__global__ __launch_bounds__(256) void init_kernel(const float* __restrict__ bq,
                                                   const float* __restrict__ bk,
                                                   const float* __restrict__ bv,
                                                   float* __restrict__ denom,
                                                   float* __restrict__ bcat) {
  int i = blockIdx.x * 256 + threadIdx.x;
  if (i < 18432) denom[i] = 0.0f;
  else if (i < 19968) {
    int k = i - 18432;
    bcat[k] = (k < 512) ? bq[k] : (k < 1024) ? bk[k - 512] : bv[k - 1024];
  }
}

// ---- x[b][c][s] fp32 -> xs[b][s][c] bf16 (64x64 LDS tiles) ----
__global__ __launch_bounds__(256) void transpose_bf16_kernel(
    const float* __restrict__ x, const float* __restrict__ xt,
    unsigned short* __restrict__ xs, unsigned short* __restrict__ xts) {
  const int S = 2304, C = 768;
  const int z = blockIdx.z;
  const float* src = (z < 8) ? x : xt;
  unsigned short* dst = (z < 8) ? xs : xts;
  const int b = z & 7;
  src += (size_t)b * C * S;
  dst += (size_t)b * S * C;
  __shared__ float tile[64][65];
  const int s0 = blockIdx.x * 64, c0 = blockIdx.y * 64;
  const int ls = threadIdx.x & 63, lr = threadIdx.x >> 6;
#pragma unroll
  for (int i = 0; i < 16; ++i) {
    const int c = lr + i * 4;
    tile[c][ls] = src[(size_t)(c0 + c) * S + s0 + ls];
  }
  __syncthreads();
#pragma unroll
  for (int i = 0; i < 16; ++i) {
    const int s = lr + i * 4;
    dst[(size_t)(s0 + s) * C + c0 + ls] = f2bf(tile[ls][s]);
  }
}

// Shared BK=64 K-tile body: stage [128][64]x2 (32KB LDS), 8 gload_lds/thread,
// ONE __syncthreads-pair per 64-K (halves drains vs BK=32).
#define GLOAD(gp, lp)                                                          \
  __builtin_amdgcn_global_load_lds(                                            \
      (const __attribute__((address_space(1))) void*)(gp),                     \
      (__attribute__((address_space(3))) void*)(lp), 16, 0, 0)

// ---- fused QKV projection: C[m][0..1536) = A @ wcat^T + bcat (BK=64) ----
// seg 0 -> Q[m][n], seg 1 -> K[m][n-512], seg 2 -> Vt[n-1024][m]
__global__ __launch_bounds__(256) void qkv64_kernel(
    const unsigned short* __restrict__ xs, const unsigned short* __restrict__ xts,
    const unsigned short* __restrict__ wcat, const float* __restrict__ bcat,
    unsigned short* __restrict__ Q, unsigned short* __restrict__ K,
    unsigned short* __restrict__ Vt) {
  __shared__ unsigned short lA[128 * 64];
  __shared__ unsigned short lB[128 * 64];
  const int t = threadIdx.x;
  const int m0 = blockIdx.y * 128, n0 = blockIdx.x * 128, b = blockIdx.z;
  const int seg = n0 >> 9;
  const unsigned short* A = ((seg == 0) ? xs : xts) + (size_t)b * 2304 * 768 + (size_t)m0 * 768;
  const unsigned short* Bt = wcat + (size_t)n0 * 768;
  const int lane = t & 63, wid = t >> 6;
  const int wm = (wid & 1) * 64, wn = (wid >> 1) * 64;
  const int fr = lane & 15, fq = lane >> 4;
  f32x4 acc[4][4] = {};

  for (int k0 = 0; k0 < 768; k0 += 64) {
#pragma unroll
    for (int q = 0; q < 4; ++q) {
      const int c = q * 256 + t;
      const int row = c >> 3, k8 = (c & 7) << 3;
      GLOAD(A + (size_t)row * 768 + k0 + k8, &lA[c * 8]);
      GLOAD(Bt + (size_t)row * 768 + k0 + k8, &lB[c * 8]);
    }
    __syncthreads();
#pragma unroll
    for (int ks = 0; ks < 2; ++ks) {
      bf16x8 af[4], bfr[4];
#pragma unroll
      for (int i = 0; i < 4; ++i)
        af[i] = *reinterpret_cast<const bf16x8*>(&lA[(wm + i * 16 + fr) * 64 + ks * 32 + fq * 8]);
#pragma unroll
      for (int j = 0; j < 4; ++j)
        bfr[j] = *reinterpret_cast<const bf16x8*>(&lB[(wn + j * 16 + fr) * 64 + ks * 32 + fq * 8]);
#pragma unroll
      for (int i = 0; i < 4; ++i)
#pragma unroll
        for (int j = 0; j < 4; ++j)
          acc[i][j] = __builtin_amdgcn_mfma_f32_16x16x32_bf16(af[i], bfr[j], acc[i][j], 0, 0, 0);
    }
    __syncthreads();
  }

  if (seg < 2) {
    unsigned short* Cp = ((seg == 0) ? Q : K) + (size_t)b * 2304 * 512;
#pragma unroll
    for (int j = 0; j < 4; ++j) {
      const int ng = n0 + wn + j * 16 + fr;
      const float bj = bcat[ng];
      const int col = ng - seg * 512;
#pragma unroll
      for (int i = 0; i < 4; ++i) {
        const int rbase = m0 + wm + i * 16 + fq * 4;
#pragma unroll
        for (int r = 0; r < 4; ++r)
          Cp[(size_t)(rbase + r) * 512 + col] = f2bf(acc[i][j][r] + bj);
      }
    }
  } else {
    unsigned short* Cp = Vt + (size_t)b * 512 * 2304;
#pragma unroll
    for (int j = 0; j < 4; ++j) {
      const int ng = n0 + wn + j * 16 + fr;
      const float bj = bcat[ng];
      const int d = ng - 1024;
#pragma unroll
      for (int i = 0; i < 4; ++i) {
        const int tb = m0 + wm + i * 16 + fq * 4;
        ushort4 pk;
        pk.x = f2bf(acc[i][j][0] + bj);
        pk.y = f2bf(acc[i][j][1] + bj);
        pk.z = f2bf(acc[i][j][2] + bj);
        pk.w = f2bf(acc[i][j][3] + bj);
        *reinterpret_cast<ushort4*>(&Cp[(size_t)d * 2304 + tb]) = pk;
      }
    }
  }
}

// ---- scores: 128^2, BK=64, grid (18,18,8)=2592 blocks ----
// P = exp(Q K^T * scale - 4) bf16; denom[row] += rowsum (atomic)
__global__ __launch_bounds__(256) void scores64_kernel(
    const unsigned short* __restrict__ Qm, const unsigned short* __restrict__ Km,
    float* __restrict__ denom, unsigned short* __restrict__ P) {
  __shared__ unsigned short lA[128 * 64];
  __shared__ unsigned short lB[128 * 64];
  const int t = threadIdx.x;
  const int m0 = blockIdx.y * 128, n0 = blockIdx.x * 128, b = blockIdx.z;
  const unsigned short* A = Qm + (size_t)b * 2304 * 512 + (size_t)m0 * 512;
  const unsigned short* Bt = Km + (size_t)b * 2304 * 512 + (size_t)n0 * 512;
  const int lane = t & 63, wid = t >> 6;
  const int wm = (wid & 1) * 64, wn = (wid >> 1) * 64;
  const int fr = lane & 15, fq = lane >> 4;
  f32x4 acc[4][4] = {};

  for (int k0 = 0; k0 < 512; k0 += 64) {
#pragma unroll
    for (int q = 0; q < 4; ++q) {
      const int c = q * 256 + t;
      const int row = c >> 3, k8 = (c & 7) << 3;
      GLOAD(A + (size_t)row * 512 + k0 + k8, &lA[c * 8]);
      GLOAD(Bt + (size_t)row * 512 + k0 + k8, &lB[c * 8]);
    }
    __syncthreads();
#pragma unroll
    for (int ks = 0; ks < 2; ++ks) {
      bf16x8 af[4], bfr[4];
#pragma unroll
      for (int i = 0; i < 4; ++i)
        af[i] = *reinterpret_cast<const bf16x8*>(&lA[(wm + i * 16 + fr) * 64 + ks * 32 + fq * 8]);
#pragma unroll
      for (int j = 0; j < 4; ++j)
        bfr[j] = *reinterpret_cast<const bf16x8*>(&lB[(wn + j * 16 + fr) * 64 + ks * 32 + fq * 8]);
#pragma unroll
      for (int i = 0; i < 4; ++i)
#pragma unroll
        for (int j = 0; j < 4; ++j)
          acc[i][j] = __builtin_amdgcn_mfma_f32_16x16x32_bf16(af[i], bfr[j], acc[i][j], 0, 0, 0);
    }
    __syncthreads();
  }

  // epilogue: exp + bf16 store + atomic row denominators (validated round 2)
  unsigned short* Pp = P + (size_t)b * 2304 * 2304;
  const float SC = 0.044194173824159216f;
  float rowsum[4][4];
#pragma unroll
  for (int i = 0; i < 4; ++i)
#pragma unroll
    for (int r = 0; r < 4; ++r) rowsum[i][r] = 0.0f;
#pragma unroll
  for (int j = 0; j < 4; ++j) {
    const int col = n0 + wn + j * 16 + fr;
#pragma unroll
    for (int i = 0; i < 4; ++i) {
      const int rbase = m0 + wm + i * 16 + fq * 4;
#pragma unroll
      for (int r = 0; r < 4; ++r) {
        const float e = __expf(acc[i][j][r] * SC - 4.0f);
        rowsum[i][r] += e;
        Pp[(size_t)(rbase + r) * 2304 + col] = f2bf(e);
      }
    }
  }
#pragma unroll
  for (int i = 0; i < 4; ++i)
#pragma unroll
    for (int r = 0; r < 4; ++r) {
      float s = rowsum[i][r];
#pragma unroll
      for (int o = 8; o >= 1; o >>= 1) s += __shfl_xor(s, o, 16);
      if (fr == 0)
        atomicAdd(&denom[(size_t)b * 2304 + m0 + wm + i * 16 + fq * 4 + r], s);
    }
}

// ---- PV split-K=2: partial[m][n] = sum_{k in chunk} P[m][k] Vt[n][k] ----
// bz = b*2 + chunk; chunk0 -> out (raw), chunk1 -> part (raw). BK=64.
__global__ __launch_bounds__(256) void pv64_kernel(
    const unsigned short* __restrict__ P, const unsigned short* __restrict__ Vt,
    float* __restrict__ Out, float* __restrict__ Part) {
  __shared__ unsigned short lA[128 * 64];
  __shared__ unsigned short lB[128 * 64];
  const int t = threadIdx.x;
  const int m0 = blockIdx.y * 128, n0 = blockIdx.x * 128;
  const int b = blockIdx.z >> 1, chunk = blockIdx.z & 1;
  const unsigned short* A = P + (size_t)b * 2304 * 2304 + (size_t)m0 * 2304 + (size_t)chunk * 1152;
  const unsigned short* Bt = Vt + (size_t)b * 512 * 2304 + (size_t)n0 * 2304 + (size_t)chunk * 1152;
  const int lane = t & 63, wid = t >> 6;
  const int wm = (wid & 1) * 64, wn = (wid >> 1) * 64;
  const int fr = lane & 15, fq = lane >> 4;
  f32x4 acc[4][4] = {};

  for (int k0 = 0; k0 < 1152; k0 += 64) {
#pragma unroll
    for (int q = 0; q < 4; ++q) {
      const int c = q * 256 + t;
      const int row = c >> 3, k8 = (c & 7) << 3;
      GLOAD(A + (size_t)row * 2304 + k0 + k8, &lA[c * 8]);
      GLOAD(Bt + (size_t)row * 2304 + k0 + k8, &lB[c * 8]);
    }
    __syncthreads();
#pragma unroll
    for (int ks = 0; ks < 2; ++ks) {
      bf16x8 af[4], bfr[4];
#pragma unroll
      for (int i = 0; i < 4; ++i)
        af[i] = *reinterpret_cast<const bf16x8*>(&lA[(wm + i * 16 + fr) * 64 + ks * 32 + fq * 8]);
#pragma unroll
      for (int j = 0; j < 4; ++j)
        bfr[j] = *reinterpret_cast<const bf16x8*>(&lB[(wn + j * 16 + fr) * 64 + ks * 32 + fq * 8]);
#pragma unroll
      for (int i = 0; i < 4; ++i)
#pragma unroll
        for (int j = 0; j < 4; ++j)
          acc[i][j] = __builtin_amdgcn_mfma_f32_16x16x32_bf16(af[i], bfr[j], acc[i][j], 0, 0, 0);
    }
    __syncthreads();
  }

  float* Cp = ((chunk == 0) ? Out : Part) + (size_t)b * 2304 * 512;
#pragma unroll
  for (int j = 0; j < 4; ++j) {
    const int col = n0 + wn + j * 16 + fr;
#pragma unroll
    for (int i = 0; i < 4; ++i) {
      const int rbase = m0 + wm + i * 16 + fq * 4;
#pragma unroll
      for (int r = 0; r < 4; ++r)
        Cp[(size_t)(rbase + r) * 512 + col] = acc[i][j][r];
    }
  }
}

// ---- combine: out = (out + part) / denom[row], float4 per thread ----
__global__ __launch_bounds__(256) void combine_kernel(
    float* __restrict__ Out, const float* __restrict__ Part,
    const float* __restrict__ denom) {
  const int i = blockIdx.x * 256 + threadIdx.x;  // float4 index, 2359296 total
  const float4 a = reinterpret_cast<const float4*>(Out)[i];
  const float4 p = reinterpret_cast<const float4*>(Part)[i];
  const float inv = 1.0f / denom[i >> 7];  // 128 float4s per 512-wide row
  float4 o;
  o.x = (a.x + p.x) * inv; o.y = (a.y + p.y) * inv;
  o.z = (a.z + p.z) * inv; o.w = (a.w + p.w) * inv;
  reinterpret_cast<float4*>(Out)[i] = o;
}

extern "C" void kernel_launch(void* const* d_in, const int* in_sizes, int n_in,
                              void* d_out, int out_size, void* d_ws, size_t ws_size,
                              hipStream_t stream) {
  const float* x  = (const float*)d_in[0];
  const float* xt = (const float*)d_in[1];
  const float* wq = (const float*)d_in[2];
  const float* bq = (const float*)d_in[3];
  const float* wk = (const float*)d_in[4];
  const float* bk = (const float*)d_in[5];
  const float* wv = (const float*)d_in[6];
  const float* bv = (const float*)d_in[7];
  float* out = (float*)d_out;
  unsigned short* ws = (unsigned short*)d_ws;

  unsigned short* Q    = ws;
  unsigned short* Kb   = ws + 9437184;
  unsigned short* Vt   = ws + 18874368;
  float* part  = (float*)ws;              // aliases Q+K (dead during PV), 9437184 f32
  unsigned short* P    = ws + 28311552;   // 85MB region
  unsigned short* xs   = ws + 28311552;   // aliases P (dead before P written)
  unsigned short* xts  = ws + 42467328;
  unsigned short* wcat = ws + 56623104;   // wq|wk|wv contiguous (1536x768)
  float* bcat  = (float*)(ws + 57802752); // 1536 f32 (inside P region, dead early)
  float* denom = (float*)(ws + 70778880); // 18432 f32, after P

  convw3_kernel<<<1152, 256, 0, stream>>>(wq, wk, wv, wcat);
  init_kernel<<<78, 256, 0, stream>>>(bq, bk, bv, denom, bcat);
  transpose_bf16_kernel<<<dim3(36, 12, 16), 256, 0, stream>>>(x, xt, xs, xts);

  // fused Q|K|V projection
  qkv64_kernel<<<dim3(12, 18, 8), 256, 0, stream>>>(xs, xts, wcat, bcat, Q, Kb, Vt);

  // P = exp(Q K^T / sqrt(D) - 4), denom[row] = sum_t P
  scores64_kernel<<<dim3(18, 18, 8), 256, 0, stream>>>(Q, Kb, denom, P);

  // PV partials (split-K=2), then combine with 1/denom
  pv64_kernel<<<dim3(4, 18, 16), 256, 0, stream>>>(P, Vt, out, part);
  combine_kernel<<<9216, 256, 0, stream>>>(out, part, denom);
}

// Round 7
// 277.238 us; speedup vs baseline: 1.1601x; 1.1601x over previous
//
#include <hip/hip_runtime.h>
#include <stdint.h>

// CrossAttentionHead: B=8, C=768, S=T=2304, D=512.
// transpose/cvt -> qkv8 (256^2 8-phase, counted vmcnt, T2 swizzle) ->
// scores8 (same template, exp epilogue + atomic row denom) ->
// pv (m97 128^2 BK=32, known-good, 1/denom epilogue).
//
// 8-phase ledger (per iteration i, tiles u=2i @dbuf0 p1-4, v=2i+1 @dbuf1 p5-8):
//   reads:  p1 B01(u)+A03(u)[12], p2 B23(u)[4], p3 A47(u)[8], p4 none,
//           p5-p8 same on v.
//   stages: p1 T(2i+1).A0, p2 .A1, p3 T(2i+2).B0, p4 .B1, p5 .A0, p6 .A1,
//           p7 T(2i+3).B0, p8 .B1   (each region staged >=2 barriers after
//           its last read; checked region-by-region).
//   vmcnt(4) at p4 (gates tile 2i+1) and p8 (gates tile 2i+2); exact count =
//   loads issued after gated tile's last load. Last iter: vmcnt(0) at p4.
//
// Workspace (ushort elems):
//   Q[0,..) K[9437184,..) Vt[18874368,..)  (each 9,437,184)
//   P@28311552 (42,467,328 elems, 85MB); aliased inside P (dead before P):
//   xs@28311552, xts@42467328, wcat@56623104 (wq|wk|wv, 1536x768),
//   bcat(f32)@ushort 57802752; denom(f32,18432)@ushort 70778880.

typedef __bf16 bf16x8 __attribute__((ext_vector_type(8)));
typedef float f32x4 __attribute__((ext_vector_type(4)));

__device__ __forceinline__ unsigned short f2bf(float f) {
  union { float f; unsigned int u; } c; c.f = f;
  return (unsigned short)((c.u + 0x7fffu + ((c.u >> 16) & 1u)) >> 16); // RNE
}

#define GLOAD(gp, lp)                                                          \
  __builtin_amdgcn_global_load_lds(                                            \
      (const __attribute__((address_space(1))) void*)(gp),                     \
      (__attribute__((address_space(3))) void*)(lp), 16, 0, 0)

// ---- all three weights fp32 -> bf16 into contiguous wcat ----
__global__ __launch_bounds__(256) void convw3_kernel(const float* __restrict__ wq,
                                                     const float* __restrict__ wk,
                                                     const float* __restrict__ wv,
                                                     unsigned short* __restrict__ wcat) {
  int i = (blockIdx.x * 256 + threadIdx.x) * 4;
  const float* src = (i < 393216) ? wq : (i < 786432) ? wk : wv;
  const int off = (i < 393216) ? 0 : (i < 786432) ? 393216 : 786432;
  const float4 v = *reinterpret_cast<const float4*>(src + (i - off));
  wcat[i + 0] = f2bf(v.x); wcat[i + 1] = f2bf(v.y);
  wcat[i + 2] = f2bf(v.z); wcat[i + 3] = f2bf(v.w);
}

// ---- zero denom + concat bias ----
__global__ __launch_bounds__(256) void init_kernel(const float* __restrict__ bq,
                                                   const float* __restrict__ bk,
                                                   const float* __restrict__ bv,
                                                   float* __restrict__ denom,
                                                   float* __restrict__ bcat) {
  int i = blockIdx.x * 256 + threadIdx.x;
  if (i < 18432) denom[i] = 0.0f;
  else if (i < 19968) {
    int k = i - 18432;
    bcat[k] = (k < 512) ? bq[k] : (k < 1024) ? bk[k - 512] : bv[k - 1024];
  }
}

// ---- x[b][c][s] fp32 -> xs[b][s][c] bf16 (64x64 LDS tiles) ----
__global__ __launch_bounds__(256) void transpose_bf16_kernel(
    const float* __restrict__ x, const float* __restrict__ xt,
    unsigned short* __restrict__ xs, unsigned short* __restrict__ xts) {
  const int S = 2304, C = 768;
  const int z = blockIdx.z;
  const float* src = (z < 8) ? x : xt;
  unsigned short* dst = (z < 8) ? xs : xts;
  const int b = z & 7;
  src += (size_t)b * C * S;
  dst += (size_t)b * S * C;
  __shared__ float tile[64][65];
  const int s0 = blockIdx.x * 64, c0 = blockIdx.y * 64;
  const int ls = threadIdx.x & 63, lr = threadIdx.x >> 6;
#pragma unroll
  for (int i = 0; i < 16; ++i) {
    const int c = lr + i * 4;
    tile[c][ls] = src[(size_t)(c0 + c) * S + s0 + ls];
  }
  __syncthreads();
#pragma unroll
  for (int i = 0; i < 16; ++i) {
    const int s = lr + i * 4;
    dst[(size_t)(s0 + s) * C + c0 + ls] = f2bf(tile[ls][s]);
  }
}

// ================= 8-phase 256x256 GEMM-BT core =================
// LDS regions (16KB each, 128KB total): idx = dbuf*4 + side*2 + half
//   side 0 = A (rows m0..m0+255), side 1 = B (rows n0..n0+255); half = row>>7.
// Swizzle (T2, both sides): LDS 16B-slot sl holds global slot sl^(rh&7).

// stage one half-tile (128 rows x 64 cols bf16 = 1024 chunks, 2 per thread)
__device__ __forceinline__ void stage_half8(
    unsigned short* __restrict__ lds, const unsigned short* __restrict__ gb,
    int ldg, int tK, int side, int h, int tid, int swcol) {
  const int d = tK & 1;
  unsigned short* l0 = lds + (size_t)((d * 4 + side * 2 + h) * 8192);
  const unsigned short* g =
      gb + (size_t)(h * 128 + (tid >> 3)) * ldg + tK * 64 + swcol;
  GLOAD(g, l0 + (size_t)tid * 8);
  GLOAD(g + (size_t)64 * ldg, l0 + (size_t)(tid + 512) * 8);
}

#define RD(baseB, rh, cb)                                        \
  (*reinterpret_cast<const bf16x8*>(                             \
      reinterpret_cast<const char*>(lds) + (baseB) + (rh)*128 + (cb)))

#define PH_READ_A0(ABASE)                              \
  _Pragma("unroll") for (int mf = 0; mf < 4; ++mf) {   \
    a[mf][0] = RD(ABASE, mf * 16 + fr, cb0);           \
    a[mf][1] = RD(ABASE, mf * 16 + fr, cb1);           \
  }
#define PH_READ_A4(ABASE)                              \
  _Pragma("unroll") for (int mf = 0; mf < 4; ++mf) {   \
    a[mf][0] = RD(ABASE, 64 + mf * 16 + fr, cb0);      \
    a[mf][1] = RD(ABASE, 64 + mf * 16 + fr, cb1);      \
  }
#define PH_READ_B01(BBASE)                             \
  _Pragma("unroll") for (int nf = 0; nf < 2; ++nf) {   \
    b01[nf][0] = RD(BBASE, brh + nf * 16, cb0);        \
    b01[nf][1] = RD(BBASE, brh + nf * 16, cb1);        \
  }
#define PH_READ_B23(BBASE)                             \
  _Pragma("unroll") for (int nf = 0; nf < 2; ++nf) {   \
    b23[nf][0] = RD(BBASE, brh + 32 + nf * 16, cb0);   \
    b23[nf][1] = RD(BBASE, brh + 32 + nf * 16, cb1);   \
  }

#define BARRIER_MFMA(MB, NB, BF)                                      \
  __builtin_amdgcn_s_barrier();                                       \
  asm volatile("s_waitcnt lgkmcnt(0)" ::: "memory");                  \
  __builtin_amdgcn_sched_barrier(0);                                  \
  __builtin_amdgcn_s_setprio(1);                                      \
  _Pragma("unroll") for (int mf = 0; mf < 4; ++mf) {                  \
    acc[MB + mf][NB + 0] = __builtin_amdgcn_mfma_f32_16x16x32_bf16(   \
        a[mf][0], BF[0][0], acc[MB + mf][NB + 0], 0, 0, 0);           \
    acc[MB + mf][NB + 0] = __builtin_amdgcn_mfma_f32_16x16x32_bf16(   \
        a[mf][1], BF[0][1], acc[MB + mf][NB + 0], 0, 0, 0);           \
    acc[MB + mf][NB + 1] = __builtin_amdgcn_mfma_f32_16x16x32_bf16(   \
        a[mf][0], BF[1][0], acc[MB + mf][NB + 1], 0, 0, 0);           \
    acc[MB + mf][NB + 1] = __builtin_amdgcn_mfma_f32_16x16x32_bf16(   \
        a[mf][1], BF[1][1], acc[MB + mf][NB + 1], 0, 0, 0);           \
  }                                                                   \
  __builtin_amdgcn_s_setprio(0);                                      \
  __builtin_amdgcn_s_barrier();

template <int NT>
__device__ __forceinline__ void gemm8_core(
    const unsigned short* __restrict__ Ab, const unsigned short* __restrict__ Bb,
    int lda, int ldb, unsigned short* __restrict__ lds, f32x4 (&acc)[8][4]) {
  const int t = threadIdx.x;
  const int lane = t & 63, wid = t >> 6;
  const int wr = wid >> 2, wc = wid & 3;
  const int fr = lane & 15, fq = lane >> 4;
  const int swm = (fr & 7) << 4;
  const int cb0 = (fq * 16) ^ swm;
  const int cb1 = (64 + fq * 16) ^ swm;
  const int brh = (wc & 1) * 64 + fr;
  const int aB0 = (0 + wr) * 16384, aB1 = (4 + wr) * 16384;
  const int bB0 = (2 + (wc >> 1)) * 16384, bB1 = (6 + (wc >> 1)) * 16384;
  const int swcol = (((t & 7) ^ ((t >> 3) & 7))) * 8;

  bf16x8 a[4][2], b01[2][2], b23[2][2];

  // prologue: T0.B0,B1,A0,A1, T1.B0,B1 (12 loads); drain all but last 4
  stage_half8(lds, Bb, ldb, 0, 1, 0, t, swcol);
  stage_half8(lds, Bb, ldb, 0, 1, 1, t, swcol);
  stage_half8(lds, Ab, lda, 0, 0, 0, t, swcol);
  stage_half8(lds, Ab, lda, 0, 0, 1, t, swcol);
  stage_half8(lds, Bb, ldb, 1, 1, 0, t, swcol);
  stage_half8(lds, Bb, ldb, 1, 1, 1, t, swcol);
  asm volatile("s_waitcnt vmcnt(4)" ::: "memory");
  __builtin_amdgcn_s_barrier();

  const int NI = NT / 2;
#pragma unroll 1
  for (int i = 0; i < NI; ++i) {
    const bool more = (i + 1 < NI);
    const int tu1 = 2 * i + 1, tu2 = 2 * i + 2, tu3 = 2 * i + 3;
    // ---- P1: read B01(u)+A03(u); stage T(2i+1).A0 ----
    PH_READ_B01(bB0); PH_READ_A0(aB0);
    stage_half8(lds, Ab, lda, tu1, 0, 0, t, swcol);
    BARRIER_MFMA(0, 0, b01);
    // ---- P2: read B23(u); stage T(2i+1).A1 ----
    PH_READ_B23(bB0);
    stage_half8(lds, Ab, lda, tu1, 0, 1, t, swcol);
    BARRIER_MFMA(0, 2, b23);
    // ---- P3: read A47(u); stage T(2i+2).B0 ----
    PH_READ_A4(aB0);
    if (more) stage_half8(lds, Bb, ldb, tu2, 1, 0, t, swcol);
    BARRIER_MFMA(4, 2, b23);
    // ---- P4: stage T(2i+2).B1; gate tile 2i+1 ----
    if (more) {
      stage_half8(lds, Bb, ldb, tu2, 1, 1, t, swcol);
      asm volatile("s_waitcnt vmcnt(4)" ::: "memory");
    } else {
      asm volatile("s_waitcnt vmcnt(0)" ::: "memory");
    }
    BARRIER_MFMA(4, 0, b01);
    // ---- P5: read B01(v)+A03(v); stage T(2i+2).A0 ----
    PH_READ_B01(bB1); PH_READ_A0(aB1);
    if (more) stage_half8(lds, Ab, lda, tu2, 0, 0, t, swcol);
    BARRIER_MFMA(0, 0, b01);
    // ---- P6: read B23(v); stage T(2i+2).A1 ----
    PH_READ_B23(bB1);
    if (more) stage_half8(lds, Ab, lda, tu2, 0, 1, t, swcol);
    BARRIER_MFMA(0, 2, b23);
    // ---- P7: read A47(v); stage T(2i+3).B0 ----
    PH_READ_A4(aB1);
    if (more) stage_half8(lds, Bb, ldb, tu3, 1, 0, t, swcol);
    BARRIER_MFMA(4, 2, b23);
    // ---- P8: stage T(2i+3).B1; gate tile 2i+2 ----
    if (more) {
      stage_half8(lds, Bb, ldb, tu3, 1, 1, t, swcol);
      asm volatile("s_waitcnt vmcnt(4)" ::: "memory");
    }
    BARRIER_MFMA(4, 0, b01);
  }
}

// ---- fused QKV projection, 8-phase 256^2, K=768 (NT=12) ----
__global__ __launch_bounds__(512) void qkv8_kernel(
    const unsigned short* __restrict__ xs, const unsigned short* __restrict__ xts,
    const unsigned short* __restrict__ wcat, const float* __restrict__ bcat,
    unsigned short* __restrict__ Q, unsigned short* __restrict__ K,
    unsigned short* __restrict__ Vt) {
  extern __shared__ unsigned short lds[];
  const int m0 = blockIdx.y * 256, n0 = blockIdx.x * 256, b = blockIdx.z;
  const int seg = n0 >> 9;
  const unsigned short* Ab =
      ((seg == 0) ? xs : xts) + (size_t)b * 2304 * 768 + (size_t)m0 * 768;
  const unsigned short* Bb = wcat + (size_t)n0 * 768;
  f32x4 acc[8][4] = {};
  gemm8_core<12>(Ab, Bb, 768, 768, lds, acc);

  const int t = threadIdx.x;
  const int lane = t & 63, wid = t >> 6;
  const int wr = wid >> 2, wc = wid & 3;
  const int fr = lane & 15, fq = lane >> 4;
  if (seg < 2) {
    unsigned short* Cp = ((seg == 0) ? Q : K) + (size_t)b * 2304 * 512;
#pragma unroll
    for (int nf = 0; nf < 4; ++nf) {
      const int ng = n0 + wc * 64 + nf * 16 + fr;
      const float bj = bcat[ng];
      const int col = ng - seg * 512;
#pragma unroll
      for (int mf = 0; mf < 8; ++mf) {
        const int rbase = m0 + wr * 128 + mf * 16 + fq * 4;
#pragma unroll
        for (int r = 0; r < 4; ++r)
          Cp[(size_t)(rbase + r) * 512 + col] = f2bf(acc[mf][nf][r] + bj);
      }
    }
  } else {
    unsigned short* Cp = Vt + (size_t)b * 512 * 2304;
#pragma unroll
    for (int nf = 0; nf < 4; ++nf) {
      const int ng = n0 + wc * 64 + nf * 16 + fr;
      const float bj = bcat[ng];
      const int d = ng - 1024;
#pragma unroll
      for (int mf = 0; mf < 8; ++mf) {
        const int tb = m0 + wr * 128 + mf * 16 + fq * 4;
        ushort4 pk;
        pk.x = f2bf(acc[mf][nf][0] + bj);
        pk.y = f2bf(acc[mf][nf][1] + bj);
        pk.z = f2bf(acc[mf][nf][2] + bj);
        pk.w = f2bf(acc[mf][nf][3] + bj);
        *reinterpret_cast<ushort4*>(&Cp[(size_t)d * 2304 + tb]) = pk;
      }
    }
  }
}

// ---- scores, 8-phase 256^2, K=512 (NT=8): P = exp(QK^T*sc - 4), denom += ----
__global__ __launch_bounds__(512) void scores8_kernel(
    const unsigned short* __restrict__ Qm, const unsigned short* __restrict__ Km,
    float* __restrict__ denom, unsigned short* __restrict__ P) {
  extern __shared__ unsigned short lds[];
  const int m0 = blockIdx.y * 256, n0 = blockIdx.x * 256, b = blockIdx.z;
  const unsigned short* Ab = Qm + (size_t)b * 2304 * 512 + (size_t)m0 * 512;
  const unsigned short* Bb = Km + (size_t)b * 2304 * 512 + (size_t)n0 * 512;
  f32x4 acc[8][4] = {};
  gemm8_core<8>(Ab, Bb, 512, 512, lds, acc);

  const int t = threadIdx.x;
  const int lane = t & 63, wid = t >> 6;
  const int wr = wid >> 2, wc = wid & 3;
  const int fr = lane & 15, fq = lane >> 4;
  unsigned short* Pp = P + (size_t)b * 2304 * 2304;
  const float SC = 0.044194173824159216f;
#pragma unroll
  for (int mf = 0; mf < 8; ++mf) {
    float rs[4] = {0.f, 0.f, 0.f, 0.f};
    const int rbase = m0 + wr * 128 + mf * 16 + fq * 4;
#pragma unroll
    for (int nf = 0; nf < 4; ++nf) {
      const int col = n0 + wc * 64 + nf * 16 + fr;
#pragma unroll
      for (int r = 0; r < 4; ++r) {
        const float e = __expf(acc[mf][nf][r] * SC - 4.0f);
        rs[r] += e;
        Pp[(size_t)(rbase + r) * 2304 + col] = f2bf(e);
      }
    }
#pragma unroll
    for (int r = 0; r < 4; ++r) {
      float s = rs[r];
#pragma unroll
      for (int o = 8; o >= 1; o >>= 1) s += __shfl_xor(s, o, 16);
      if (fr == 0) atomicAdd(&denom[(size_t)b * 2304 + rbase + r], s);
    }
  }
}

// ---- PV: m97 128^2 BK=32 (round-5 known-good), out = (P @ Vt^T)/denom ----
__global__ __launch_bounds__(256) void pv_kernel(
    const unsigned short* __restrict__ P, const unsigned short* __restrict__ Vt,
    const float* __restrict__ denom, float* __restrict__ Out) {
  __shared__ unsigned short lA[128 * 32];
  __shared__ unsigned short lB[128 * 32];
  const int t = threadIdx.x;
  const int m0 = blockIdx.y * 128, n0 = blockIdx.x * 128, b = blockIdx.z;
  const unsigned short* A = P + (size_t)b * 2304 * 2304 + (size_t)m0 * 2304;
  const unsigned short* Bt = Vt + (size_t)b * 512 * 2304 + (size_t)n0 * 2304;
  const int lane = t & 63, wid = t >> 6;
  const int wm = (wid & 1) * 64, wn = (wid >> 1) * 64;
  const int fr = lane & 15, fq = lane >> 4;
  f32x4 acc[4][4] = {};

  for (int k0 = 0; k0 < 2304; k0 += 32) {
#pragma unroll
    for (int it = 0; it < 2; ++it) {
      const int c = it * 256 + t;
      const int row = c >> 2, k8 = (c & 3) << 3;
      GLOAD(A + (size_t)row * 2304 + k0 + k8, &lA[c * 8]);
      GLOAD(Bt + (size_t)row * 2304 + k0 + k8, &lB[c * 8]);
    }
    __syncthreads();
    bf16x8 af[4], bfr[4];
#pragma unroll
    for (int i = 0; i < 4; ++i)
      af[i] = *reinterpret_cast<const bf16x8*>(&lA[(wm + i * 16 + fr) * 32 + fq * 8]);
#pragma unroll
    for (int j = 0; j < 4; ++j)
      bfr[j] = *reinterpret_cast<const bf16x8*>(&lB[(wn + j * 16 + fr) * 32 + fq * 8]);
#pragma unroll
    for (int i = 0; i < 4; ++i)
#pragma unroll
      for (int j = 0; j < 4; ++j)
        acc[i][j] = __builtin_amdgcn_mfma_f32_16x16x32_bf16(af[i], bfr[j], acc[i][j], 0, 0, 0);
    __syncthreads();
  }

  float* Cp = Out + (size_t)b * 2304 * 512;
  float invd[4][4];
#pragma unroll
  for (int i = 0; i < 4; ++i)
#pragma unroll
    for (int r = 0; r < 4; ++r)
      invd[i][r] = 1.0f / denom[(size_t)b * 2304 + m0 + wm + i * 16 + fq * 4 + r];
#pragma unroll
  for (int j = 0; j < 4; ++j) {
    const int col = n0 + wn + j * 16 + fr;
#pragma unroll
    for (int i = 0; i < 4; ++i) {
      const int rbase = m0 + wm + i * 16 + fq * 4;
#pragma unroll
      for (int r = 0; r < 4; ++r)
        Cp[(size_t)(rbase + r) * 512 + col] = acc[i][j][r] * invd[i][r];
    }
  }
}

extern "C" void kernel_launch(void* const* d_in, const int* in_sizes, int n_in,
                              void* d_out, int out_size, void* d_ws, size_t ws_size,
                              hipStream_t stream) {
  const float* x  = (const float*)d_in[0];
  const float* xt = (const float*)d_in[1];
  const float* wq = (const float*)d_in[2];
  const float* bq = (const float*)d_in[3];
  const float* wk = (const float*)d_in[4];
  const float* bk = (const float*)d_in[5];
  const float* wv = (const float*)d_in[6];
  const float* bv = (const float*)d_in[7];
  float* out = (float*)d_out;
  unsigned short* ws = (unsigned short*)d_ws;

  unsigned short* Q    = ws;
  unsigned short* Kb   = ws + 9437184;
  unsigned short* Vt   = ws + 18874368;
  unsigned short* P    = ws + 28311552;   // 85MB region
  unsigned short* xs   = ws + 28311552;   // aliases P (dead before P written)
  unsigned short* xts  = ws + 42467328;
  unsigned short* wcat = ws + 56623104;   // wq|wk|wv contiguous (1536x768)
  float* bcat  = (float*)(ws + 57802752); // 1536 f32 (inside P region, dead early)
  float* denom = (float*)(ws + 70778880); // 18432 f32, after P

  static int attr_set = 0;
  if (!attr_set) {
    hipFuncSetAttribute((const void*)qkv8_kernel,
                        hipFuncAttributeMaxDynamicSharedMemorySize, 131072);
    hipFuncSetAttribute((const void*)scores8_kernel,
                        hipFuncAttributeMaxDynamicSharedMemorySize, 131072);
    attr_set = 1;
  }

  convw3_kernel<<<1152, 256, 0, stream>>>(wq, wk, wv, wcat);
  init_kernel<<<78, 256, 0, stream>>>(bq, bk, bv, denom, bcat);
  transpose_bf16_kernel<<<dim3(36, 12, 16), 256, 0, stream>>>(x, xt, xs, xts);

  // fused Q|K|V projection (8-phase 256^2)
  qkv8_kernel<<<dim3(6, 9, 8), 512, 131072, stream>>>(xs, xts, wcat, bcat, Q, Kb, Vt);

  // P = exp(Q K^T / sqrt(D) - 4), denom[row] = sum_t P (8-phase 256^2)
  scores8_kernel<<<dim3(9, 9, 8), 512, 131072, stream>>>(Q, Kb, denom, P);

  // out = (P @ V) / denom[row]
  pv_kernel<<<dim3(4, 18, 8), 256, 0, stream>>>(P, Vt, denom, out);
}

// Round 8
// 241.052 us; speedup vs baseline: 1.3343x; 1.1501x over previous
//
#include <hip/hip_runtime.h>
#include <stdint.h>

// CrossAttentionHead: B=8, C=768, S=T=2304, D=512.
// transpose/cvt -> qkv8 (256^2 8-phase, counted vmcnt, T2 swizzle) ->
// scores8 (same template, exp epilogue + atomic row denom) ->
// pv8 (same template, NT=36, 1/denom fp32 epilogue).
//
// 8-phase ledger (per iteration i, tiles u=2i @dbuf0 p1-4, v=2i+1 @dbuf1 p5-8):
//   reads:  p1 B01(u)+A03(u)[12], p2 B23(u)[4], p3 A47(u)[8], p4 none,
//           p5-p8 same on v.
//   stages: p1 T(2i+1).A0, p2 .A1, p3 T(2i+2).B0, p4 .B1, p5 .A0, p6 .A1,
//           p7 T(2i+3).B0, p8 .B1   (each region staged >=2 barriers after
//           its last read; checked region-by-region).
//   vmcnt(4) at p4 (gates tile 2i+1) and p8 (gates tile 2i+2); exact count =
//   loads issued after gated tile's last load. Last iter: vmcnt(0) at p4.
//
// Workspace (ushort elems):
//   Q[0,..) K[9437184,..) Vt[18874368,..)  (each 9,437,184)
//   P@28311552 (42,467,328 elems, 85MB); aliased inside P (dead before P):
//   xs@28311552, xts@42467328, wcat@56623104 (wq|wk|wv, 1536x768),
//   bcat(f32)@ushort 57802752; denom(f32,18432)@ushort 70778880.

typedef __bf16 bf16x8 __attribute__((ext_vector_type(8)));
typedef float f32x4 __attribute__((ext_vector_type(4)));

__device__ __forceinline__ unsigned short f2bf(float f) {
  union { float f; unsigned int u; } c; c.f = f;
  return (unsigned short)((c.u + 0x7fffu + ((c.u >> 16) & 1u)) >> 16); // RNE
}

#define GLOAD(gp, lp)                                                          \
  __builtin_amdgcn_global_load_lds(                                            \
      (const __attribute__((address_space(1))) void*)(gp),                     \
      (__attribute__((address_space(3))) void*)(lp), 16, 0, 0)

// ---- all three weights fp32 -> bf16 into contiguous wcat ----
__global__ __launch_bounds__(256) void convw3_kernel(const float* __restrict__ wq,
                                                     const float* __restrict__ wk,
                                                     const float* __restrict__ wv,
                                                     unsigned short* __restrict__ wcat) {
  int i = (blockIdx.x * 256 + threadIdx.x) * 4;
  const float* src = (i < 393216) ? wq : (i < 786432) ? wk : wv;
  const int off = (i < 393216) ? 0 : (i < 786432) ? 393216 : 786432;
  const float4 v = *reinterpret_cast<const float4*>(src + (i - off));
  wcat[i + 0] = f2bf(v.x); wcat[i + 1] = f2bf(v.y);
  wcat[i + 2] = f2bf(v.z); wcat[i + 3] = f2bf(v.w);
}

// ---- zero denom + concat bias ----
__global__ __launch_bounds__(256) void init_kernel(const float* __restrict__ bq,
                                                   const float* __restrict__ bk,
                                                   const float* __restrict__ bv,
                                                   float* __restrict__ denom,
                                                   float* __restrict__ bcat) {
  int i = blockIdx.x * 256 + threadIdx.x;
  if (i < 18432) denom[i] = 0.0f;
  else if (i < 19968) {
    int k = i - 18432;
    bcat[k] = (k < 512) ? bq[k] : (k < 1024) ? bk[k - 512] : bv[k - 1024];
  }
}

// ---- x[b][c][s] fp32 -> xs[b][s][c] bf16 (64x64 LDS tiles) ----
__global__ __launch_bounds__(256) void transpose_bf16_kernel(
    const float* __restrict__ x, const float* __restrict__ xt,
    unsigned short* __restrict__ xs, unsigned short* __restrict__ xts) {
  const int S = 2304, C = 768;
  const int z = blockIdx.z;
  const float* src = (z < 8) ? x : xt;
  unsigned short* dst = (z < 8) ? xs : xts;
  const int b = z & 7;
  src += (size_t)b * C * S;
  dst += (size_t)b * S * C;
  __shared__ float tile[64][65];
  const int s0 = blockIdx.x * 64, c0 = blockIdx.y * 64;
  const int ls = threadIdx.x & 63, lr = threadIdx.x >> 6;
#pragma unroll
  for (int i = 0; i < 16; ++i) {
    const int c = lr + i * 4;
    tile[c][ls] = src[(size_t)(c0 + c) * S + s0 + ls];
  }
  __syncthreads();
#pragma unroll
  for (int i = 0; i < 16; ++i) {
    const int s = lr + i * 4;
    dst[(size_t)(s0 + s) * C + c0 + ls] = f2bf(tile[ls][s]);
  }
}

// ================= 8-phase 256x256 GEMM-BT core =================
// LDS regions (16KB each, 128KB total): idx = dbuf*4 + side*2 + half
//   side 0 = A (rows m0..m0+255), side 1 = B (rows n0..n0+255); half = row>>7.
// Swizzle (T2, both sides): LDS 16B-slot sl holds global slot sl^(rh&7).

// stage one half-tile (128 rows x 64 cols bf16 = 1024 chunks, 2 per thread)
__device__ __forceinline__ void stage_half8(
    unsigned short* __restrict__ lds, const unsigned short* __restrict__ gb,
    int ldg, int tK, int side, int h, int tid, int swcol) {
  const int d = tK & 1;
  unsigned short* l0 = lds + (size_t)((d * 4 + side * 2 + h) * 8192);
  const unsigned short* g =
      gb + (size_t)(h * 128 + (tid >> 3)) * ldg + tK * 64 + swcol;
  GLOAD(g, l0 + (size_t)tid * 8);
  GLOAD(g + (size_t)64 * ldg, l0 + (size_t)(tid + 512) * 8);
}

#define RD(baseB, rh, cb)                                        \
  (*reinterpret_cast<const bf16x8*>(                             \
      reinterpret_cast<const char*>(lds) + (baseB) + (rh)*128 + (cb)))

#define PH_READ_A0(ABASE)                              \
  _Pragma("unroll") for (int mf = 0; mf < 4; ++mf) {   \
    a[mf][0] = RD(ABASE, mf * 16 + fr, cb0);           \
    a[mf][1] = RD(ABASE, mf * 16 + fr, cb1);           \
  }
#define PH_READ_A4(ABASE)                              \
  _Pragma("unroll") for (int mf = 0; mf < 4; ++mf) {   \
    a[mf][0] = RD(ABASE, 64 + mf * 16 + fr, cb0);      \
    a[mf][1] = RD(ABASE, 64 + mf * 16 + fr, cb1);      \
  }
#define PH_READ_B01(BBASE)                             \
  _Pragma("unroll") for (int nf = 0; nf < 2; ++nf) {   \
    b01[nf][0] = RD(BBASE, brh + nf * 16, cb0);        \
    b01[nf][1] = RD(BBASE, brh + nf * 16, cb1);        \
  }
#define PH_READ_B23(BBASE)                             \
  _Pragma("unroll") for (int nf = 0; nf < 2; ++nf) {   \
    b23[nf][0] = RD(BBASE, brh + 32 + nf * 16, cb0);   \
    b23[nf][1] = RD(BBASE, brh + 32 + nf * 16, cb1);   \
  }

#define BARRIER_MFMA(MB, NB, BF)                                      \
  __builtin_amdgcn_s_barrier();                                       \
  asm volatile("s_waitcnt lgkmcnt(0)" ::: "memory");                  \
  __builtin_amdgcn_sched_barrier(0);                                  \
  __builtin_amdgcn_s_setprio(1);                                      \
  _Pragma("unroll") for (int mf = 0; mf < 4; ++mf) {                  \
    acc[MB + mf][NB + 0] = __builtin_amdgcn_mfma_f32_16x16x32_bf16(   \
        a[mf][0], BF[0][0], acc[MB + mf][NB + 0], 0, 0, 0);           \
    acc[MB + mf][NB + 0] = __builtin_amdgcn_mfma_f32_16x16x32_bf16(   \
        a[mf][1], BF[0][1], acc[MB + mf][NB + 0], 0, 0, 0);           \
    acc[MB + mf][NB + 1] = __builtin_amdgcn_mfma_f32_16x16x32_bf16(   \
        a[mf][0], BF[1][0], acc[MB + mf][NB + 1], 0, 0, 0);           \
    acc[MB + mf][NB + 1] = __builtin_amdgcn_mfma_f32_16x16x32_bf16(   \
        a[mf][1], BF[1][1], acc[MB + mf][NB + 1], 0, 0, 0);           \
  }                                                                   \
  __builtin_amdgcn_s_setprio(0);                                      \
  __builtin_amdgcn_s_barrier();

template <int NT>
__device__ __forceinline__ void gemm8_core(
    const unsigned short* __restrict__ Ab, const unsigned short* __restrict__ Bb,
    int lda, int ldb, unsigned short* __restrict__ lds, f32x4 (&acc)[8][4]) {
  const int t = threadIdx.x;
  const int lane = t & 63, wid = t >> 6;
  const int wr = wid >> 2, wc = wid & 3;
  const int fr = lane & 15, fq = lane >> 4;
  const int swm = (fr & 7) << 4;
  const int cb0 = (fq * 16) ^ swm;
  const int cb1 = (64 + fq * 16) ^ swm;
  const int brh = (wc & 1) * 64 + fr;
  const int aB0 = (0 + wr) * 16384, aB1 = (4 + wr) * 16384;
  const int bB0 = (2 + (wc >> 1)) * 16384, bB1 = (6 + (wc >> 1)) * 16384;
  const int swcol = (((t & 7) ^ ((t >> 3) & 7))) * 8;

  bf16x8 a[4][2], b01[2][2], b23[2][2];

  // prologue: T0.B0,B1,A0,A1, T1.B0,B1 (12 loads); drain all but last 4
  stage_half8(lds, Bb, ldb, 0, 1, 0, t, swcol);
  stage_half8(lds, Bb, ldb, 0, 1, 1, t, swcol);
  stage_half8(lds, Ab, lda, 0, 0, 0, t, swcol);
  stage_half8(lds, Ab, lda, 0, 0, 1, t, swcol);
  stage_half8(lds, Bb, ldb, 1, 1, 0, t, swcol);
  stage_half8(lds, Bb, ldb, 1, 1, 1, t, swcol);
  asm volatile("s_waitcnt vmcnt(4)" ::: "memory");
  __builtin_amdgcn_s_barrier();

  const int NI = NT / 2;
#pragma unroll 1
  for (int i = 0; i < NI; ++i) {
    const bool more = (i + 1 < NI);
    const int tu1 = 2 * i + 1, tu2 = 2 * i + 2, tu3 = 2 * i + 3;
    // ---- P1: read B01(u)+A03(u); stage T(2i+1).A0 ----
    PH_READ_B01(bB0); PH_READ_A0(aB0);
    stage_half8(lds, Ab, lda, tu1, 0, 0, t, swcol);
    BARRIER_MFMA(0, 0, b01);
    // ---- P2: read B23(u); stage T(2i+1).A1 ----
    PH_READ_B23(bB0);
    stage_half8(lds, Ab, lda, tu1, 0, 1, t, swcol);
    BARRIER_MFMA(0, 2, b23);
    // ---- P3: read A47(u); stage T(2i+2).B0 ----
    PH_READ_A4(aB0);
    if (more) stage_half8(lds, Bb, ldb, tu2, 1, 0, t, swcol);
    BARRIER_MFMA(4, 2, b23);
    // ---- P4: stage T(2i+2).B1; gate tile 2i+1 ----
    if (more) {
      stage_half8(lds, Bb, ldb, tu2, 1, 1, t, swcol);
      asm volatile("s_waitcnt vmcnt(4)" ::: "memory");
    } else {
      asm volatile("s_waitcnt vmcnt(0)" ::: "memory");
    }
    BARRIER_MFMA(4, 0, b01);
    // ---- P5: read B01(v)+A03(v); stage T(2i+2).A0 ----
    PH_READ_B01(bB1); PH_READ_A0(aB1);
    if (more) stage_half8(lds, Ab, lda, tu2, 0, 0, t, swcol);
    BARRIER_MFMA(0, 0, b01);
    // ---- P6: read B23(v); stage T(2i+2).A1 ----
    PH_READ_B23(bB1);
    if (more) stage_half8(lds, Ab, lda, tu2, 0, 1, t, swcol);
    BARRIER_MFMA(0, 2, b23);
    // ---- P7: read A47(v); stage T(2i+3).B0 ----
    PH_READ_A4(aB1);
    if (more) stage_half8(lds, Bb, ldb, tu3, 1, 0, t, swcol);
    BARRIER_MFMA(4, 2, b23);
    // ---- P8: stage T(2i+3).B1; gate tile 2i+2 ----
    if (more) {
      stage_half8(lds, Bb, ldb, tu3, 1, 1, t, swcol);
      asm volatile("s_waitcnt vmcnt(4)" ::: "memory");
    }
    BARRIER_MFMA(4, 0, b01);
  }
}

// ---- fused QKV projection, 8-phase 256^2, K=768 (NT=12) ----
__global__ __launch_bounds__(512) void qkv8_kernel(
    const unsigned short* __restrict__ xs, const unsigned short* __restrict__ xts,
    const unsigned short* __restrict__ wcat, const float* __restrict__ bcat,
    unsigned short* __restrict__ Q, unsigned short* __restrict__ K,
    unsigned short* __restrict__ Vt) {
  extern __shared__ unsigned short lds[];
  const int m0 = blockIdx.y * 256, n0 = blockIdx.x * 256, b = blockIdx.z;
  const int seg = n0 >> 9;
  const unsigned short* Ab =
      ((seg == 0) ? xs : xts) + (size_t)b * 2304 * 768 + (size_t)m0 * 768;
  const unsigned short* Bb = wcat + (size_t)n0 * 768;
  f32x4 acc[8][4] = {};
  gemm8_core<12>(Ab, Bb, 768, 768, lds, acc);

  const int t = threadIdx.x;
  const int lane = t & 63, wid = t >> 6;
  const int wr = wid >> 2, wc = wid & 3;
  const int fr = lane & 15, fq = lane >> 4;
  if (seg < 2) {
    unsigned short* Cp = ((seg == 0) ? Q : K) + (size_t)b * 2304 * 512;
#pragma unroll
    for (int nf = 0; nf < 4; ++nf) {
      const int ng = n0 + wc * 64 + nf * 16 + fr;
      const float bj = bcat[ng];
      const int col = ng - seg * 512;
#pragma unroll
      for (int mf = 0; mf < 8; ++mf) {
        const int rbase = m0 + wr * 128 + mf * 16 + fq * 4;
#pragma unroll
        for (int r = 0; r < 4; ++r)
          Cp[(size_t)(rbase + r) * 512 + col] = f2bf(acc[mf][nf][r] + bj);
      }
    }
  } else {
    unsigned short* Cp = Vt + (size_t)b * 512 * 2304;
#pragma unroll
    for (int nf = 0; nf < 4; ++nf) {
      const int ng = n0 + wc * 64 + nf * 16 + fr;
      const float bj = bcat[ng];
      const int d = ng - 1024;
#pragma unroll
      for (int mf = 0; mf < 8; ++mf) {
        const int tb = m0 + wr * 128 + mf * 16 + fq * 4;
        ushort4 pk;
        pk.x = f2bf(acc[mf][nf][0] + bj);
        pk.y = f2bf(acc[mf][nf][1] + bj);
        pk.z = f2bf(acc[mf][nf][2] + bj);
        pk.w = f2bf(acc[mf][nf][3] + bj);
        *reinterpret_cast<ushort4*>(&Cp[(size_t)d * 2304 + tb]) = pk;
      }
    }
  }
}

// ---- scores, 8-phase 256^2, K=512 (NT=8): P = exp(QK^T*sc - 4), denom += ----
__global__ __launch_bounds__(512) void scores8_kernel(
    const unsigned short* __restrict__ Qm, const unsigned short* __restrict__ Km,
    float* __restrict__ denom, unsigned short* __restrict__ P) {
  extern __shared__ unsigned short lds[];
  const int m0 = blockIdx.y * 256, n0 = blockIdx.x * 256, b = blockIdx.z;
  const unsigned short* Ab = Qm + (size_t)b * 2304 * 512 + (size_t)m0 * 512;
  const unsigned short* Bb = Km + (size_t)b * 2304 * 512 + (size_t)n0 * 512;
  f32x4 acc[8][4] = {};
  gemm8_core<8>(Ab, Bb, 512, 512, lds, acc);

  const int t = threadIdx.x;
  const int lane = t & 63, wid = t >> 6;
  const int wr = wid >> 2, wc = wid & 3;
  const int fr = lane & 15, fq = lane >> 4;
  unsigned short* Pp = P + (size_t)b * 2304 * 2304;
  const float SC = 0.044194173824159216f;
#pragma unroll
  for (int mf = 0; mf < 8; ++mf) {
    float rs[4] = {0.f, 0.f, 0.f, 0.f};
    const int rbase = m0 + wr * 128 + mf * 16 + fq * 4;
#pragma unroll
    for (int nf = 0; nf < 4; ++nf) {
      const int col = n0 + wc * 64 + nf * 16 + fr;
#pragma unroll
      for (int r = 0; r < 4; ++r) {
        const float e = __expf(acc[mf][nf][r] * SC - 4.0f);
        rs[r] += e;
        Pp[(size_t)(rbase + r) * 2304 + col] = f2bf(e);
      }
    }
#pragma unroll
    for (int r = 0; r < 4; ++r) {
      float s = rs[r];
#pragma unroll
      for (int o = 8; o >= 1; o >>= 1) s += __shfl_xor(s, o, 16);
      if (fr == 0) atomicAdd(&denom[(size_t)b * 2304 + rbase + r], s);
    }
  }
}

// ---- PV, 8-phase 256^2, K=2304 (NT=36): out = (P @ Vt^T)/denom, fp32 ----
__global__ __launch_bounds__(512) void pv8_kernel(
    const unsigned short* __restrict__ P, const unsigned short* __restrict__ Vt,
    const float* __restrict__ denom, float* __restrict__ Out) {
  extern __shared__ unsigned short lds[];
  const int m0 = blockIdx.y * 256, n0 = blockIdx.x * 256, b = blockIdx.z;
  const unsigned short* Ab = P + (size_t)b * 2304 * 2304 + (size_t)m0 * 2304;
  const unsigned short* Bb = Vt + (size_t)b * 512 * 2304 + (size_t)n0 * 2304;
  f32x4 acc[8][4] = {};
  gemm8_core<36>(Ab, Bb, 2304, 2304, lds, acc);

  const int t = threadIdx.x;
  const int lane = t & 63, wid = t >> 6;
  const int wr = wid >> 2, wc = wid & 3;
  const int fr = lane & 15, fq = lane >> 4;
  float* Cp = Out + (size_t)b * 2304 * 512;
  const float* dn = denom + (size_t)b * 2304;
#pragma unroll
  for (int mf = 0; mf < 8; ++mf) {
    const int rbase = m0 + wr * 128 + mf * 16 + fq * 4;
#pragma unroll
    for (int r = 0; r < 4; ++r) {
      const float inv = 1.0f / dn[rbase + r];
#pragma unroll
      for (int nf = 0; nf < 4; ++nf) {
        const int col = n0 + wc * 64 + nf * 16 + fr;
        Cp[(size_t)(rbase + r) * 512 + col] = acc[mf][nf][r] * inv;
      }
    }
  }
}

extern "C" void kernel_launch(void* const* d_in, const int* in_sizes, int n_in,
                              void* d_out, int out_size, void* d_ws, size_t ws_size,
                              hipStream_t stream) {
  const float* x  = (const float*)d_in[0];
  const float* xt = (const float*)d_in[1];
  const float* wq = (const float*)d_in[2];
  const float* bq = (const float*)d_in[3];
  const float* wk = (const float*)d_in[4];
  const float* bk = (const float*)d_in[5];
  const float* wv = (const float*)d_in[6];
  const float* bv = (const float*)d_in[7];
  float* out = (float*)d_out;
  unsigned short* ws = (unsigned short*)d_ws;

  unsigned short* Q    = ws;
  unsigned short* Kb   = ws + 9437184;
  unsigned short* Vt   = ws + 18874368;
  unsigned short* P    = ws + 28311552;   // 85MB region
  unsigned short* xs   = ws + 28311552;   // aliases P (dead before P written)
  unsigned short* xts  = ws + 42467328;
  unsigned short* wcat = ws + 56623104;   // wq|wk|wv contiguous (1536x768)
  float* bcat  = (float*)(ws + 57802752); // 1536 f32 (inside P region, dead early)
  float* denom = (float*)(ws + 70778880); // 18432 f32, after P

  static int attr_set = 0;
  if (!attr_set) {
    hipFuncSetAttribute((const void*)qkv8_kernel,
                        hipFuncAttributeMaxDynamicSharedMemorySize, 131072);
    hipFuncSetAttribute((const void*)scores8_kernel,
                        hipFuncAttributeMaxDynamicSharedMemorySize, 131072);
    hipFuncSetAttribute((const void*)pv8_kernel,
                        hipFuncAttributeMaxDynamicSharedMemorySize, 131072);
    attr_set = 1;
  }

  convw3_kernel<<<1152, 256, 0, stream>>>(wq, wk, wv, wcat);
  init_kernel<<<78, 256, 0, stream>>>(bq, bk, bv, denom, bcat);
  transpose_bf16_kernel<<<dim3(36, 12, 16), 256, 0, stream>>>(x, xt, xs, xts);

  // fused Q|K|V projection (8-phase 256^2)
  qkv8_kernel<<<dim3(6, 9, 8), 512, 131072, stream>>>(xs, xts, wcat, bcat, Q, Kb, Vt);

  // P = exp(Q K^T / sqrt(D) - 4), denom[row] = sum_t P (8-phase 256^2)
  scores8_kernel<<<dim3(9, 9, 8), 512, 131072, stream>>>(Q, Kb, denom, P);

  // out = (P @ V) / denom[row] (8-phase 256^2, NT=36)
  pv8_kernel<<<dim3(2, 9, 8), 512, 131072, stream>>>(P, Vt, denom, out);
}

// Round 9
// 218.852 us; speedup vs baseline: 1.4696x; 1.1014x over previous
//
#include <hip/hip_runtime.h>
#include <stdint.h>

// CrossAttentionHead: B=8, C=768, S=T=2304, D=512.
// transpose/cvt -> qkv8 (256^2 8-phase, counted vmcnt, T2 swizzle) ->
// scores8 (same template, exp epilogue + atomic row denom) ->
// pv8 (same template, NT=36, 1/denom fp32 epilogue).
// Round-9: batch->XCD bijective block swizzle on all 8-phase kernels
// (each XCD's private L2 serves exactly one batch's panels; intra-batch
// order chosen so the pinned panel + cycling panels fit 4MB L2).
//
// 8-phase ledger (per iteration i, tiles u=2i @dbuf0 p1-4, v=2i+1 @dbuf1 p5-8):
//   reads:  p1 B01(u)+A03(u)[12], p2 B23(u)[4], p3 A47(u)[8], p4 none,
//           p5-p8 same on v.
//   stages: p1 T(2i+1).A0, p2 .A1, p3 T(2i+2).B0, p4 .B1, p5 .A0, p6 .A1,
//           p7 T(2i+3).B0, p8 .B1   (each region staged >=2 barriers after
//           its last read; checked region-by-region).
//   vmcnt(4) at p4 (gates tile 2i+1) and p8 (gates tile 2i+2); last iter:
//   vmcnt(0) at p4.
//
// Workspace (ushort elems):
//   Q[0,..) K[9437184,..) Vt[18874368,..)  (each 9,437,184)
//   P@28311552 (42,467,328 elems, 85MB); aliased inside P (dead before P):
//   xs@28311552, xts@42467328, wcat@56623104 (wq|wk|wv, 1536x768),
//   bcat(f32)@ushort 57802752; denom(f32,18432)@ushort 70778880.

typedef __bf16 bf16x8 __attribute__((ext_vector_type(8)));
typedef float f32x4 __attribute__((ext_vector_type(4)));

__device__ __forceinline__ unsigned short f2bf(float f) {
  union { float f; unsigned int u; } c; c.f = f;
  return (unsigned short)((c.u + 0x7fffu + ((c.u >> 16) & 1u)) >> 16); // RNE
}

#define GLOAD(gp, lp)                                                          \
  __builtin_amdgcn_global_load_lds(                                            \
      (const __attribute__((address_space(1))) void*)(gp),                     \
      (__attribute__((address_space(3))) void*)(lp), 16, 0, 0)

// ---- all three weights fp32 -> bf16 into contiguous wcat ----
__global__ __launch_bounds__(256) void convw3_kernel(const float* __restrict__ wq,
                                                     const float* __restrict__ wk,
                                                     const float* __restrict__ wv,
                                                     unsigned short* __restrict__ wcat) {
  int i = (blockIdx.x * 256 + threadIdx.x) * 4;
  const float* src = (i < 393216) ? wq : (i < 786432) ? wk : wv;
  const int off = (i < 393216) ? 0 : (i < 786432) ? 393216 : 786432;
  const float4 v = *reinterpret_cast<const float4*>(src + (i - off));
  wcat[i + 0] = f2bf(v.x); wcat[i + 1] = f2bf(v.y);
  wcat[i + 2] = f2bf(v.z); wcat[i + 3] = f2bf(v.w);
}

// ---- zero denom + concat bias ----
__global__ __launch_bounds__(256) void init_kernel(const float* __restrict__ bq,
                                                   const float* __restrict__ bk,
                                                   const float* __restrict__ bv,
                                                   float* __restrict__ denom,
                                                   float* __restrict__ bcat) {
  int i = blockIdx.x * 256 + threadIdx.x;
  if (i < 18432) denom[i] = 0.0f;
  else if (i < 19968) {
    int k = i - 18432;
    bcat[k] = (k < 512) ? bq[k] : (k < 1024) ? bk[k - 512] : bv[k - 1024];
  }
}

// ---- x[b][c][s] fp32 -> xs[b][s][c] bf16 (64x64 LDS tiles) ----
__global__ __launch_bounds__(256) void transpose_bf16_kernel(
    const float* __restrict__ x, const float* __restrict__ xt,
    unsigned short* __restrict__ xs, unsigned short* __restrict__ xts) {
  const int S = 2304, C = 768;
  const int z = blockIdx.z;
  const float* src = (z < 8) ? x : xt;
  unsigned short* dst = (z < 8) ? xs : xts;
  const int b = z & 7;
  src += (size_t)b * C * S;
  dst += (size_t)b * S * C;
  __shared__ float tile[64][65];
  const int s0 = blockIdx.x * 64, c0 = blockIdx.y * 64;
  const int ls = threadIdx.x & 63, lr = threadIdx.x >> 6;
#pragma unroll
  for (int i = 0; i < 16; ++i) {
    const int c = lr + i * 4;
    tile[c][ls] = src[(size_t)(c0 + c) * S + s0 + ls];
  }
  __syncthreads();
#pragma unroll
  for (int i = 0; i < 16; ++i) {
    const int s = lr + i * 4;
    dst[(size_t)(s0 + s) * C + c0 + ls] = f2bf(tile[ls][s]);
  }
}

// ================= 8-phase 256x256 GEMM-BT core =================
// LDS regions (16KB each, 128KB total): idx = dbuf*4 + side*2 + half
//   side 0 = A (rows m0..m0+255), side 1 = B (rows n0..n0+255); half = row>>7.
// Swizzle (T2, both sides): LDS 16B-slot sl holds global slot sl^(rh&7).

// stage one half-tile (128 rows x 64 cols bf16 = 1024 chunks, 2 per thread)
__device__ __forceinline__ void stage_half8(
    unsigned short* __restrict__ lds, const unsigned short* __restrict__ gb,
    int ldg, int tK, int side, int h, int tid, int swcol) {
  const int d = tK & 1;
  unsigned short* l0 = lds + (size_t)((d * 4 + side * 2 + h) * 8192);
  const unsigned short* g =
      gb + (size_t)(h * 128 + (tid >> 3)) * ldg + tK * 64 + swcol;
  GLOAD(g, l0 + (size_t)tid * 8);
  GLOAD(g + (size_t)64 * ldg, l0 + (size_t)(tid + 512) * 8);
}

#define RD(baseB, rh, cb)                                        \
  (*reinterpret_cast<const bf16x8*>(                             \
      reinterpret_cast<const char*>(lds) + (baseB) + (rh)*128 + (cb)))

#define PH_READ_A0(ABASE)                              \
  _Pragma("unroll") for (int mf = 0; mf < 4; ++mf) {   \
    a[mf][0] = RD(ABASE, mf * 16 + fr, cb0);           \
    a[mf][1] = RD(ABASE, mf * 16 + fr, cb1);           \
  }
#define PH_READ_A4(ABASE)                              \
  _Pragma("unroll") for (int mf = 0; mf < 4; ++mf) {   \
    a[mf][0] = RD(ABASE, 64 + mf * 16 + fr, cb0);      \
    a[mf][1] = RD(ABASE, 64 + mf * 16 + fr, cb1);      \
  }
#define PH_READ_B01(BBASE)                             \
  _Pragma("unroll") for (int nf = 0; nf < 2; ++nf) {   \
    b01[nf][0] = RD(BBASE, brh + nf * 16, cb0);        \
    b01[nf][1] = RD(BBASE, brh + nf * 16, cb1);        \
  }
#define PH_READ_B23(BBASE)                             \
  _Pragma("unroll") for (int nf = 0; nf < 2; ++nf) {   \
    b23[nf][0] = RD(BBASE, brh + 32 + nf * 16, cb0);   \
    b23[nf][1] = RD(BBASE, brh + 32 + nf * 16, cb1);   \
  }

#define BARRIER_MFMA(MB, NB, BF)                                      \
  __builtin_amdgcn_s_barrier();                                       \
  asm volatile("s_waitcnt lgkmcnt(0)" ::: "memory");                  \
  __builtin_amdgcn_sched_barrier(0);                                  \
  __builtin_amdgcn_s_setprio(1);                                      \
  _Pragma("unroll") for (int mf = 0; mf < 4; ++mf) {                  \
    acc[MB + mf][NB + 0] = __builtin_amdgcn_mfma_f32_16x16x32_bf16(   \
        a[mf][0], BF[0][0], acc[MB + mf][NB + 0], 0, 0, 0);           \
    acc[MB + mf][NB + 0] = __builtin_amdgcn_mfma_f32_16x16x32_bf16(   \
        a[mf][1], BF[0][1], acc[MB + mf][NB + 0], 0, 0, 0);           \
    acc[MB + mf][NB + 1] = __builtin_amdgcn_mfma_f32_16x16x32_bf16(   \
        a[mf][0], BF[1][0], acc[MB + mf][NB + 1], 0, 0, 0);           \
    acc[MB + mf][NB + 1] = __builtin_amdgcn_mfma_f32_16x16x32_bf16(   \
        a[mf][1], BF[1][1], acc[MB + mf][NB + 1], 0, 0, 0);           \
  }                                                                   \
  __builtin_amdgcn_s_setprio(0);                                      \
  __builtin_amdgcn_s_barrier();

template <int NT>
__device__ __forceinline__ void gemm8_core(
    const unsigned short* __restrict__ Ab, const unsigned short* __restrict__ Bb,
    int lda, int ldb, unsigned short* __restrict__ lds, f32x4 (&acc)[8][4]) {
  const int t = threadIdx.x;
  const int lane = t & 63, wid = t >> 6;
  const int wr = wid >> 2, wc = wid & 3;
  const int fr = lane & 15, fq = lane >> 4;
  const int swm = (fr & 7) << 4;
  const int cb0 = (fq * 16) ^ swm;
  const int cb1 = (64 + fq * 16) ^ swm;
  const int brh = (wc & 1) * 64 + fr;
  const int aB0 = (0 + wr) * 16384, aB1 = (4 + wr) * 16384;
  const int bB0 = (2 + (wc >> 1)) * 16384, bB1 = (6 + (wc >> 1)) * 16384;
  const int swcol = (((t & 7) ^ ((t >> 3) & 7))) * 8;

  bf16x8 a[4][2], b01[2][2], b23[2][2];

  // prologue: T0.B0,B1,A0,A1, T1.B0,B1 (12 loads); drain all but last 4
  stage_half8(lds, Bb, ldb, 0, 1, 0, t, swcol);
  stage_half8(lds, Bb, ldb, 0, 1, 1, t, swcol);
  stage_half8(lds, Ab, lda, 0, 0, 0, t, swcol);
  stage_half8(lds, Ab, lda, 0, 0, 1, t, swcol);
  stage_half8(lds, Bb, ldb, 1, 1, 0, t, swcol);
  stage_half8(lds, Bb, ldb, 1, 1, 1, t, swcol);
  asm volatile("s_waitcnt vmcnt(4)" ::: "memory");
  __builtin_amdgcn_s_barrier();

  const int NI = NT / 2;
#pragma unroll 1
  for (int i = 0; i < NI; ++i) {
    const bool more = (i + 1 < NI);
    const int tu1 = 2 * i + 1, tu2 = 2 * i + 2, tu3 = 2 * i + 3;
    // ---- P1: read B01(u)+A03(u); stage T(2i+1).A0 ----
    PH_READ_B01(bB0); PH_READ_A0(aB0);
    stage_half8(lds, Ab, lda, tu1, 0, 0, t, swcol);
    BARRIER_MFMA(0, 0, b01);
    // ---- P2: read B23(u); stage T(2i+1).A1 ----
    PH_READ_B23(bB0);
    stage_half8(lds, Ab, lda, tu1, 0, 1, t, swcol);
    BARRIER_MFMA(0, 2, b23);
    // ---- P3: read A47(u); stage T(2i+2).B0 ----
    PH_READ_A4(aB0);
    if (more) stage_half8(lds, Bb, ldb, tu2, 1, 0, t, swcol);
    BARRIER_MFMA(4, 2, b23);
    // ---- P4: stage T(2i+2).B1; gate tile 2i+1 ----
    if (more) {
      stage_half8(lds, Bb, ldb, tu2, 1, 1, t, swcol);
      asm volatile("s_waitcnt vmcnt(4)" ::: "memory");
    } else {
      asm volatile("s_waitcnt vmcnt(0)" ::: "memory");
    }
    BARRIER_MFMA(4, 0, b01);
    // ---- P5: read B01(v)+A03(v); stage T(2i+2).A0 ----
    PH_READ_B01(bB1); PH_READ_A0(aB1);
    if (more) stage_half8(lds, Ab, lda, tu2, 0, 0, t, swcol);
    BARRIER_MFMA(0, 0, b01);
    // ---- P6: read B23(v); stage T(2i+2).A1 ----
    PH_READ_B23(bB1);
    if (more) stage_half8(lds, Ab, lda, tu2, 0, 1, t, swcol);
    BARRIER_MFMA(0, 2, b23);
    // ---- P7: read A47(v); stage T(2i+3).B0 ----
    PH_READ_A4(aB1);
    if (more) stage_half8(lds, Bb, ldb, tu3, 1, 0, t, swcol);
    BARRIER_MFMA(4, 2, b23);
    // ---- P8: stage T(2i+3).B1; gate tile 2i+2 ----
    if (more) {
      stage_half8(lds, Bb, ldb, tu3, 1, 1, t, swcol);
      asm volatile("s_waitcnt vmcnt(4)" ::: "memory");
    }
    BARRIER_MFMA(4, 0, b01);
  }
}

// ---- fused QKV projection, 8-phase 256^2, K=768 (NT=12) ----
// swizzle: batch = lin&7; within batch, n fastest (wcat panels cycle, A pinned)
__global__ __launch_bounds__(512) void qkv8_kernel(
    const unsigned short* __restrict__ xs, const unsigned short* __restrict__ xts,
    const unsigned short* __restrict__ wcat, const float* __restrict__ bcat,
    unsigned short* __restrict__ Q, unsigned short* __restrict__ K,
    unsigned short* __restrict__ Vt) {
  extern __shared__ unsigned short lds[];
  const int lin = blockIdx.x + 6 * (blockIdx.y + 9 * blockIdx.z);
  const int b = lin & 7, idx = lin >> 3;       // idx in [0,54)
  const int byp = idx / 6, bxp = idx - byp * 6;
  const int m0 = byp * 256, n0 = bxp * 256;
  const int seg = n0 >> 9;
  const unsigned short* Ab =
      ((seg == 0) ? xs : xts) + (size_t)b * 2304 * 768 + (size_t)m0 * 768;
  const unsigned short* Bb = wcat + (size_t)n0 * 768;
  f32x4 acc[8][4] = {};
  gemm8_core<12>(Ab, Bb, 768, 768, lds, acc);

  const int t = threadIdx.x;
  const int lane = t & 63, wid = t >> 6;
  const int wr = wid >> 2, wc = wid & 3;
  const int fr = lane & 15, fq = lane >> 4;
  if (seg < 2) {
    unsigned short* Cp = ((seg == 0) ? Q : K) + (size_t)b * 2304 * 512;
#pragma unroll
    for (int nf = 0; nf < 4; ++nf) {
      const int ng = n0 + wc * 64 + nf * 16 + fr;
      const float bj = bcat[ng];
      const int col = ng - seg * 512;
#pragma unroll
      for (int mf = 0; mf < 8; ++mf) {
        const int rbase = m0 + wr * 128 + mf * 16 + fq * 4;
#pragma unroll
        for (int r = 0; r < 4; ++r)
          Cp[(size_t)(rbase + r) * 512 + col] = f2bf(acc[mf][nf][r] + bj);
      }
    }
  } else {
    unsigned short* Cp = Vt + (size_t)b * 512 * 2304;
#pragma unroll
    for (int nf = 0; nf < 4; ++nf) {
      const int ng = n0 + wc * 64 + nf * 16 + fr;
      const float bj = bcat[ng];
      const int d = ng - 1024;
#pragma unroll
      for (int mf = 0; mf < 8; ++mf) {
        const int tb = m0 + wr * 128 + mf * 16 + fq * 4;
        ushort4 pk;
        pk.x = f2bf(acc[mf][nf][0] + bj);
        pk.y = f2bf(acc[mf][nf][1] + bj);
        pk.z = f2bf(acc[mf][nf][2] + bj);
        pk.w = f2bf(acc[mf][nf][3] + bj);
        *reinterpret_cast<ushort4*>(&Cp[(size_t)d * 2304 + tb]) = pk;
      }
    }
  }
}

// ---- scores, 8-phase 256^2, K=512 (NT=8): P = exp(QK^T*sc - 4), denom += ----
// swizzle: batch = lin&7; within batch, m (Q panel) fastest, K panel pinned
__global__ __launch_bounds__(512) void scores8_kernel(
    const unsigned short* __restrict__ Qm, const unsigned short* __restrict__ Km,
    float* __restrict__ denom, unsigned short* __restrict__ P) {
  extern __shared__ unsigned short lds[];
  const int lin = blockIdx.x + 9 * (blockIdx.y + 9 * blockIdx.z);
  const int b = lin & 7, idx = lin >> 3;       // idx in [0,81)
  const int bxp = idx / 9, byp = idx - bxp * 9;
  const int m0 = byp * 256, n0 = bxp * 256;
  const unsigned short* Ab = Qm + (size_t)b * 2304 * 512 + (size_t)m0 * 512;
  const unsigned short* Bb = Km + (size_t)b * 2304 * 512 + (size_t)n0 * 512;
  f32x4 acc[8][4] = {};
  gemm8_core<8>(Ab, Bb, 512, 512, lds, acc);

  const int t = threadIdx.x;
  const int lane = t & 63, wid = t >> 6;
  const int wr = wid >> 2, wc = wid & 3;
  const int fr = lane & 15, fq = lane >> 4;
  unsigned short* Pp = P + (size_t)b * 2304 * 2304;
  const float SC = 0.044194173824159216f;
#pragma unroll
  for (int mf = 0; mf < 8; ++mf) {
    float rs[4] = {0.f, 0.f, 0.f, 0.f};
    const int rbase = m0 + wr * 128 + mf * 16 + fq * 4;
#pragma unroll
    for (int nf = 0; nf < 4; ++nf) {
      const int col = n0 + wc * 64 + nf * 16 + fr;
#pragma unroll
      for (int r = 0; r < 4; ++r) {
        const float e = __expf(acc[mf][nf][r] * SC - 4.0f);
        rs[r] += e;
        Pp[(size_t)(rbase + r) * 2304 + col] = f2bf(e);
      }
    }
#pragma unroll
    for (int r = 0; r < 4; ++r) {
      float s = rs[r];
#pragma unroll
      for (int o = 8; o >= 1; o >>= 1) s += __shfl_xor(s, o, 16);
      if (fr == 0) atomicAdd(&denom[(size_t)b * 2304 + rbase + r], s);
    }
  }
}

// ---- PV, 8-phase 256^2, K=2304 (NT=36): out = (P @ Vt^T)/denom, fp32 ----
// swizzle: batch = lin&7; within batch, n fastest (P panel read once)
__global__ __launch_bounds__(512) void pv8_kernel(
    const unsigned short* __restrict__ P, const unsigned short* __restrict__ Vt,
    const float* __restrict__ denom, float* __restrict__ Out) {
  extern __shared__ unsigned short lds[];
  const int lin = blockIdx.x + 2 * (blockIdx.y + 9 * blockIdx.z);
  const int b = lin & 7, idx = lin >> 3;       // idx in [0,18)
  const int byp = idx >> 1, bxp = idx & 1;
  const int m0 = byp * 256, n0 = bxp * 256;
  const unsigned short* Ab = P + (size_t)b * 2304 * 2304 + (size_t)m0 * 2304;
  const unsigned short* Bb = Vt + (size_t)b * 512 * 2304 + (size_t)n0 * 2304;
  f32x4 acc[8][4] = {};
  gemm8_core<36>(Ab, Bb, 2304, 2304, lds, acc);

  const int t = threadIdx.x;
  const int lane = t & 63, wid = t >> 6;
  const int wr = wid >> 2, wc = wid & 3;
  const int fr = lane & 15, fq = lane >> 4;
  float* Cp = Out + (size_t)b * 2304 * 512;
  const float* dn = denom + (size_t)b * 2304;
#pragma unroll
  for (int mf = 0; mf < 8; ++mf) {
    const int rbase = m0 + wr * 128 + mf * 16 + fq * 4;
#pragma unroll
    for (int r = 0; r < 4; ++r) {
      const float inv = 1.0f / dn[rbase + r];
#pragma unroll
      for (int nf = 0; nf < 4; ++nf) {
        const int col = n0 + wc * 64 + nf * 16 + fr;
        Cp[(size_t)(rbase + r) * 512 + col] = acc[mf][nf][r] * inv;
      }
    }
  }
}

extern "C" void kernel_launch(void* const* d_in, const int* in_sizes, int n_in,
                              void* d_out, int out_size, void* d_ws, size_t ws_size,
                              hipStream_t stream) {
  const float* x  = (const float*)d_in[0];
  const float* xt = (const float*)d_in[1];
  const float* wq = (const float*)d_in[2];
  const float* bq = (const float*)d_in[3];
  const float* wk = (const float*)d_in[4];
  const float* bk = (const float*)d_in[5];
  const float* wv = (const float*)d_in[6];
  const float* bv = (const float*)d_in[7];
  float* out = (float*)d_out;
  unsigned short* ws = (unsigned short*)d_ws;

  unsigned short* Q    = ws;
  unsigned short* Kb   = ws + 9437184;
  unsigned short* Vt   = ws + 18874368;
  unsigned short* P    = ws + 28311552;   // 85MB region
  unsigned short* xs   = ws + 28311552;   // aliases P (dead before P written)
  unsigned short* xts  = ws + 42467328;
  unsigned short* wcat = ws + 56623104;   // wq|wk|wv contiguous (1536x768)
  float* bcat  = (float*)(ws + 57802752); // 1536 f32 (inside P region, dead early)
  float* denom = (float*)(ws + 70778880); // 18432 f32, after P

  static int attr_set = 0;
  if (!attr_set) {
    hipFuncSetAttribute((const void*)qkv8_kernel,
                        hipFuncAttributeMaxDynamicSharedMemorySize, 131072);
    hipFuncSetAttribute((const void*)scores8_kernel,
                        hipFuncAttributeMaxDynamicSharedMemorySize, 131072);
    hipFuncSetAttribute((const void*)pv8_kernel,
                        hipFuncAttributeMaxDynamicSharedMemorySize, 131072);
    attr_set = 1;
  }

  convw3_kernel<<<1152, 256, 0, stream>>>(wq, wk, wv, wcat);
  init_kernel<<<78, 256, 0, stream>>>(bq, bk, bv, denom, bcat);
  transpose_bf16_kernel<<<dim3(36, 12, 16), 256, 0, stream>>>(x, xt, xs, xts);

  // fused Q|K|V projection (8-phase 256^2)
  qkv8_kernel<<<dim3(6, 9, 8), 512, 131072, stream>>>(xs, xts, wcat, bcat, Q, Kb, Vt);

  // P = exp(Q K^T / sqrt(D) - 4), denom[row] = sum_t P (8-phase 256^2)
  scores8_kernel<<<dim3(9, 9, 8), 512, 131072, stream>>>(Q, Kb, denom, P);

  // out = (P @ V) / denom[row] (8-phase 256^2, NT=36)
  pv8_kernel<<<dim3(2, 9, 8), 512, 131072, stream>>>(P, Vt, denom, out);
}